// Round 18
// baseline (1176.596 us; speedup 1.0000x reference)
//
#include <hip/hip_runtime.h>

// N=64, T=512, D=H=512.
//   xw = x @ Wx + b   -> d_out (fp32)
//   h_t = tanh(h_{t-1} @ Wh + xw_t) -> overwrites d_out in place
//
// v16 = r17's banked optimum + gemm/scan FUSION (overlap the 45us gemm with
// the 1074us scan; the only remaining idle-resource lever).
//  - One fused kernel, grid 516 x 512thr: blocks 0-3 = scan (verbatim v7),
//    blocks 4-515 = gemm tiles, t-major order (tchunk = gb>>6, n = gb&63).
//  - Sync: gemm block release-adds cnt[tchunk] when its 64x512 tile is
//    stored; scan acquire-polls cnt ONCE PER 64 STEPS (8 polls total —
//    NOT per-step; r2/r9 showed per-step cross-block sync costs 3-16us/step).
//  - Scan waits for chunk c+1 just before the pair whose 2nd step prefetches
//    row 64(c+1)  (t%64==62). Chunk-0 wait sits after weight/LDS setup.
//  - All arithmetic bit-identical to r17 -> absmax exactly 0.01843262.
// prepack unchanged (runs first, serialized; ~8us).

typedef __attribute__((ext_vector_type(8))) short short8;
typedef __attribute__((ext_vector_type(4))) float f32x4;

#define DIM 512
#define T_S 512

union Frag { uint4 v; short8 s; unsigned short u[8]; };

static __device__ __forceinline__ unsigned short f2bf(float f) {
  union { float f; unsigned u; } v;
  v.f = f;
  unsigned r = v.u + 0x7FFFu + ((v.u >> 16) & 1u);
  return (unsigned short)(r >> 16);
}

static __device__ __forceinline__ unsigned cvt_pk_bf16(float a, float b) {
  unsigned r;
  asm("v_cvt_pk_bf16_f32 %0, %1, %2" : "=v"(r) : "v"(a), "v"(b));
  return r;  // lo16 = bf16(a), hi16 = bf16(b), RNE
}

static __device__ __forceinline__ float fast_tanh(float s) {
  float e = __builtin_amdgcn_exp2f(2.885390082f * s);
  return 1.0f - 2.0f * __builtin_amdgcn_rcpf(e + 1.0f);
}

// ---------------------------------------------------------------------------
// Pack W (512x512 fp32) into bf16 MFMA fragments (A/B-symmetric layout).
// ---------------------------------------------------------------------------
__global__ __launch_bounds__(64) void prepack(const float* __restrict__ Wx,
                                              const float* __restrict__ Wh,
                                              uint4* __restrict__ wxb,
                                              uint4* __restrict__ whb) {
  int bid = blockIdx.x;
  int mat = bid >> 9;
  int idx = bid & 511;
  int kk = idx >> 5, cc = idx & 31;
  int lane = threadIdx.x;
  int lo = lane & 15, hi = lane >> 4;
  const float* src = mat ? Wh : Wx;
  uint4* dst = mat ? whb : wxb;
  int col = cc * 16 + lo;
  int kbase = kk * 32 + hi * 8;
  Frag fr;
#pragma unroll
  for (int j = 0; j < 8; ++j)
    fr.u[j] = f2bf(src[(size_t)(kbase + j) * DIM + col]);
  dst[(kk * 32 + cc) * 64 + lane] = fr.v;
}

// ---------------------------------------------------------------------------
// Shared LDS for the fused kernel (scan blocks use it; gemm blocks don't).
// ---------------------------------------------------------------------------
__shared__ uint4 wlds[4][32][64];             // 128 KB: Wh kk=12..15
__shared__ unsigned short hbuf2[2][16 * 512]; // 32 KB ping/pong

// ---------------------------------------------------------------------------
// Chunk-readiness wait (scan side). cnt entries are 128B apart.
// ---------------------------------------------------------------------------
static __device__ __forceinline__ void wait_chunk(const unsigned* cnt, int c) {
  const unsigned* p = cnt + c * 32;
  while (__hip_atomic_load(p, __ATOMIC_RELAXED, __HIP_MEMORY_SCOPE_AGENT) < 64u)
    __builtin_amdgcn_s_sleep(8);
  (void)__hip_atomic_load(p, __ATOMIC_ACQUIRE, __HIP_MEMORY_SCOPE_AGENT);
}

// ---------------------------------------------------------------------------
// Scan step (v7 verbatim).
// ---------------------------------------------------------------------------
template <int BUF>
static __device__ __forceinline__ void step_body(
    int t, int w, int lane, const uint4 (&bw)[12][4],
    const uint4* const (&rdp)[8], uint2* const (&wrp)[4],
    float (&xwv)[16], float*& gp) {
  f32x4 acc[4];
#pragma unroll
  for (int i = 0; i < 4; ++i)
    acc[i] = (f32x4){xwv[i * 4 + 0], xwv[i * 4 + 1], xwv[i * 4 + 2], xwv[i * 4 + 3]};

  const float* lp = gp + ((t < T_S - 1) ? DIM : 0);
#pragma unroll
  for (int i = 0; i < 4; ++i) {
    float4 f = *(const float4*)(lp + i * 16);
    xwv[i * 4 + 0] = f.x; xwv[i * 4 + 1] = f.y;
    xwv[i * 4 + 2] = f.z; xwv[i * 4 + 3] = f.w;
  }

#pragma unroll
  for (int kk = 0; kk < 12; ++kk) {
    Frag hf; hf.v = rdp[kk & 7][((kk & 8) ? 32 : 0) + BUF * 1024];
#pragma unroll
    for (int i = 0; i < 4; ++i) {
      Frag a; a.v = bw[kk][i];
      acc[i] = __builtin_amdgcn_mfma_f32_16x16x32_bf16(a.s, hf.s, acc[i], 0, 0, 0);
    }
  }
#pragma unroll
  for (int kk = 12; kk < 16; ++kk) {
    Frag hf; hf.v = rdp[kk & 7][32 + BUF * 1024];
#pragma unroll
    for (int i = 0; i < 4; ++i) {
      Frag a; a.v = wlds[kk - 12][w * 4 + i][lane];
      acc[i] = __builtin_amdgcn_mfma_f32_16x16x32_bf16(a.s, hf.s, acc[i], 0, 0, 0);
    }
  }

#pragma unroll
  for (int i = 0; i < 4; ++i) {
    float h0 = fast_tanh(acc[i][0]);
    float h1 = fast_tanh(acc[i][1]);
    float h2 = fast_tanh(acc[i][2]);
    float h3 = fast_tanh(acc[i][3]);
    *(float4*)(gp + i * 16) = (float4){h0, h1, h2, h3};
    uint2 u;
    u.x = cvt_pk_bf16(h0, h1);
    u.y = cvt_pk_bf16(h2, h3);
    wrp[i][(BUF ^ 1) * 2048] = u;
  }
  gp += DIM;

  asm volatile("s_waitcnt lgkmcnt(0)" ::: "memory");
  __builtin_amdgcn_sched_barrier(0);
  __builtin_amdgcn_s_barrier();
  __builtin_amdgcn_sched_barrier(0);
}

static __device__ void scan_part(int g, const float* __restrict__ h0,
                                 const uint4* __restrict__ whb,
                                 float* __restrict__ out,
                                 const unsigned* __restrict__ cnt) {
  int w = threadIdx.x >> 6, lane = threadIdx.x & 63;
  int lo = lane & 15, hi = lane >> 4;
  int msk = (lo & 7) << 4;

  uint4 bw[12][4];
#pragma unroll
  for (int kk = 0; kk < 12; ++kk)
#pragma unroll
    for (int i = 0; i < 4; ++i)
      bw[kk][i] = whb[(kk * 32 + (w * 4 + i)) * 64 + lane];

#pragma unroll
  for (int e = 0; e < 16; ++e) {
    int idx = e * 512 + threadIdx.x;
    int s = idx >> 11, rem = idx & 2047;
    wlds[s][rem >> 6][rem & 63] = whb[((12 + s) * 32 + (rem >> 6)) * 64 + (rem & 63)];
  }

  const uint4* rdp[8];
#pragma unroll
  for (int kk = 0; kk < 8; ++kk)
    rdp[kk] = (const uint4*)((const char*)hbuf2 + lo * 1024 + ((kk * 64 + hi * 16) ^ msk));
  uint2* wrp[4];
#pragma unroll
  for (int i = 0; i < 4; ++i)
    wrp[i] = (uint2*)((char*)hbuf2 + lo * 1024 + ((128 * w + 32 * i + 8 * hi) ^ msk));

#pragma unroll
  for (int i = 0; i < 4; ++i) {
    const float* hp = h0 + (size_t)(g * 16 + lo) * DIM + w * 64 + i * 16 + hi * 4;
    float4 f = *(const float4*)hp;
    uint2 u;
    u.x = (unsigned)f2bf(f.x) | ((unsigned)f2bf(f.y) << 16);
    u.y = (unsigned)f2bf(f.z) | ((unsigned)f2bf(f.w) << 16);
    wrp[i][0] = u;
  }

  float* gp = out + ((size_t)(g * 16 + lo) * T_S) * DIM + w * 64 + hi * 4;

  // xw rows [0,64) must exist before priming (gemm chunk 0)
  wait_chunk(cnt, 0);

  float xwv[16];
#pragma unroll
  for (int i = 0; i < 4; ++i) {
    float4 f = *(const float4*)(gp + i * 16);
    xwv[i * 4 + 0] = f.x; xwv[i * 4 + 1] = f.y;
    xwv[i * 4 + 2] = f.z; xwv[i * 4 + 3] = f.w;
  }

  __syncthreads();

#pragma unroll 1
  for (int t = 0; t < T_S; t += 2) {
    // step t+1 prefetches row t+2; when t+2 enters a new chunk, wait for it
    if (((t & 63) == 62) && (t + 2 < T_S)) wait_chunk(cnt, (t + 2) >> 6);
    step_body<0>(t,     w, lane, bw, rdp, wrp, xwv, gp);
    step_body<1>(t + 1, w, lane, bw, rdp, wrp, xwv, gp);
  }
}

// ---------------------------------------------------------------------------
// Gemm tile (8 waves, 64 rows x 512 cols, t-major block order).
// gb: tchunk = gb>>6, nidx = gb&63 -> rows [nidx*512 + tchunk*64, +64).
// ---------------------------------------------------------------------------
static __device__ void gemm_part(int gb, const float* __restrict__ x,
                                 const uint4* __restrict__ wxb,
                                 const float* __restrict__ bias,
                                 float* __restrict__ out,
                                 unsigned* __restrict__ cnt) {
  int tchunk = gb >> 6, nidx = gb & 63;
  int rowbase = nidx * 512 + tchunk * 64;
  int w = threadIdx.x >> 6, lane = threadIdx.x & 63;
  int lo = lane & 15, hi = lane >> 4;

  f32x4 acc[4][4];
#pragma unroll
  for (int mi = 0; mi < 4; ++mi)
#pragma unroll
    for (int ni = 0; ni < 4; ++ni) acc[mi][ni] = (f32x4){0.f, 0.f, 0.f, 0.f};

  for (int kk = 0; kk < 16; ++kk) {
    short8 afrag[4];
#pragma unroll
    for (int mi = 0; mi < 4; ++mi) {
      const float* ap = x + (size_t)(rowbase + mi * 16 + lo) * DIM + kk * 32 + hi * 8;
      float4 f0 = *(const float4*)ap;
      float4 f1 = *(const float4*)(ap + 4);
      Frag a;
      a.u[0] = f2bf(f0.x); a.u[1] = f2bf(f0.y); a.u[2] = f2bf(f0.z); a.u[3] = f2bf(f0.w);
      a.u[4] = f2bf(f1.x); a.u[5] = f2bf(f1.y); a.u[6] = f2bf(f1.z); a.u[7] = f2bf(f1.w);
      afrag[mi] = a.s;
    }
#pragma unroll
    for (int ni = 0; ni < 4; ++ni) {
      int cc = w * 4 + ni;
      Frag b;
      b.v = wxb[(kk * 32 + cc) * 64 + lane];
#pragma unroll
      for (int mi = 0; mi < 4; ++mi)
        acc[mi][ni] = __builtin_amdgcn_mfma_f32_16x16x32_bf16(afrag[mi], b.s, acc[mi][ni], 0, 0, 0);
    }
  }
#pragma unroll
  for (int ni = 0; ni < 4; ++ni) {
    int col = w * 64 + ni * 16 + lo;
    float bv = bias[col];
#pragma unroll
    for (int mi = 0; mi < 4; ++mi)
#pragma unroll
      for (int r = 0; r < 4; ++r) {
        int row = rowbase + mi * 16 + hi * 4 + r;
        out[(size_t)row * DIM + col] = acc[mi][ni][r] + bv;
      }
  }

  // all stores of this block drained, then release the chunk counter
  asm volatile("s_waitcnt vmcnt(0)" ::: "memory");
  __syncthreads();
  if (threadIdx.x == 0)
    (void)__hip_atomic_fetch_add(cnt + tchunk * 32, 1u, __ATOMIC_RELEASE,
                                 __HIP_MEMORY_SCOPE_AGENT);
}

// ---------------------------------------------------------------------------
__global__ __launch_bounds__(512, 2) void fused(const float* __restrict__ x,
                                                const float* __restrict__ h0,
                                                const uint4* __restrict__ whb,
                                                const uint4* __restrict__ wxb,
                                                const float* __restrict__ bias,
                                                float* __restrict__ out,
                                                unsigned* __restrict__ cnt) {
  if (blockIdx.x < 4)
    scan_part(blockIdx.x, h0, whb, out, cnt);
  else
    gemm_part(blockIdx.x - 4, x, wxb, bias, out, cnt);
}

// ---------------------------------------------------------------------------
extern "C" void kernel_launch(void* const* d_in, const int* in_sizes, int n_in,
                              void* d_out, int out_size, void* d_ws, size_t ws_size,
                              hipStream_t stream) {
  const float* x  = (const float*)d_in[0];
  const float* h0 = (const float*)d_in[1];
  const float* Wx = (const float*)d_in[2];
  const float* Wh = (const float*)d_in[3];
  const float* b  = (const float*)d_in[4];
  float* out = (float*)d_out;

  char* ws = (char*)d_ws;
  uint4* whb = (uint4*)ws;                        // 512 KB
  uint4* wxb = (uint4*)(ws + 524288);             // 512 KB
  unsigned* cnt = (unsigned*)(ws + 2 * 524288);   // 8 counters x 128 B

  (void)hipMemsetAsync(cnt, 0, 1024, stream);
  prepack<<<1024, 64, 0, stream>>>(Wx, Wh, wxb, whb);
  fused<<<516, 512, 0, stream>>>(x, h0, whb, wxb, b, out, cnt);
}

// Round 19
// 1124.962 us; speedup vs baseline: 1.0459x; 1.0459x over previous
//
#include <hip/hip_runtime.h>

// N=64, T=512, D=H=512.
//   xw = x @ Wx + b   -> d_out (fp32), big MFMA GEMM
//   h_t = tanh(h_{t-1} @ Wh + xw_t) -> overwrites d_out in place
//
// FINAL (round-19 restore of the round-14/17 optimum: 1125-1126us, verified 2x).
// All axes bracketed by measurement across rounds 2-18:
//  - cross-CU h-exchange: fence 16us/step (r2), relaxed-agent 5us/step (r9)
//    vs in-block 2.1us/step -> 4 blocks is optimal parallelism width.
//  - Wh residency: 192 AGPR + 4kk LDS optimal (r8); 224/256 AGPR regress
//    (r9/r12); L2 streaming worse than LDS (r11).
//  - scheduling: setprio -36% (r13), bulk h prefetch -3% (r15), pair-split
//    epilogue overlap -97% (r16) -> compiler's v7 schedule is the floor.
//  - gemm/scan fusion: +105us contention+wait vs 45us saved (r18) -> negative.
// Scan: 4 blocks x 8 waves (2/SIMD); wave owns 64 cols; swapped-operand MFMA
// (lane owns n=lo, 4 consecutive cols/acc group); h ping-pong 2x16KB LDS
// XOR-swizzled; acc init from xw; xw(t+1) prefetch at step top; imm-offset
// LDS bases; vector epilogue (cvt_pk_bf16+ds_write_b64+float4 store); ONE raw
// s_barrier + lgkmcnt(0)/step. gemm_xw v2: 64x512 tile (x rows read once).

typedef __attribute__((ext_vector_type(8))) short short8;
typedef __attribute__((ext_vector_type(4))) float f32x4;

#define DIM 512
#define T_S 512

union Frag { uint4 v; short8 s; unsigned short u[8]; };

static __device__ __forceinline__ unsigned short f2bf(float f) {
  union { float f; unsigned u; } v;
  v.f = f;
  unsigned r = v.u + 0x7FFFu + ((v.u >> 16) & 1u);
  return (unsigned short)(r >> 16);
}

static __device__ __forceinline__ unsigned cvt_pk_bf16(float a, float b) {
  unsigned r;
  asm("v_cvt_pk_bf16_f32 %0, %1, %2" : "=v"(r) : "v"(a), "v"(b));
  return r;  // lo16 = bf16(a), hi16 = bf16(b), RNE
}

static __device__ __forceinline__ float fast_tanh(float s) {
  float e = __builtin_amdgcn_exp2f(2.885390082f * s);
  return 1.0f - 2.0f * __builtin_amdgcn_rcpf(e + 1.0f);
}

// ---------------------------------------------------------------------------
// Pack W (512x512 fp32) into bf16 MFMA fragments (A/B-symmetric layout).
// Frag (kk, cc): lane l holds W[k=32kk+8(l>>4)+j][col=16cc+(l&15)], j=0..7,
// at dst[(kk*32+cc)*64 + lane].
// ---------------------------------------------------------------------------
__global__ __launch_bounds__(64) void prepack(const float* __restrict__ Wx,
                                              const float* __restrict__ Wh,
                                              uint4* __restrict__ wxb,
                                              uint4* __restrict__ whb) {
  int bid = blockIdx.x;
  int mat = bid >> 9;
  int idx = bid & 511;
  int kk = idx >> 5, cc = idx & 31;
  int lane = threadIdx.x;
  int lo = lane & 15, hi = lane >> 4;
  const float* src = mat ? Wh : Wx;
  uint4* dst = mat ? whb : wxb;
  int col = cc * 16 + lo;
  int kbase = kk * 32 + hi * 8;
  Frag fr;
#pragma unroll
  for (int j = 0; j < 8; ++j)
    fr.u[j] = f2bf(src[(size_t)(kbase + j) * DIM + col]);
  dst[(kk * 32 + cc) * 64 + lane] = fr.v;
}

// ---------------------------------------------------------------------------
// xw = x @ Wx + b -> out (fp32). M=32768, K=N=512.
// v2: block 256 thr (4 waves), tile 64 rows x 512 cols (x rows read ONCE).
// Wave w: cc 8w..8w+7. grid = 512.
// ---------------------------------------------------------------------------
__global__ __launch_bounds__(256, 2) void gemm_xw(const float* __restrict__ x,
                                                  const uint4* __restrict__ wxb,
                                                  const float* __restrict__ bias,
                                                  float* __restrict__ out) {
  int m = blockIdx.x;
  int wave = threadIdx.x >> 6, lane = threadIdx.x & 63;
  int lo = lane & 15, hi = lane >> 4;
  int rowbase = m * 64;

  f32x4 acc[4][8];
#pragma unroll
  for (int mi = 0; mi < 4; ++mi)
#pragma unroll
    for (int ni = 0; ni < 8; ++ni) acc[mi][ni] = (f32x4){0.f, 0.f, 0.f, 0.f};

  for (int kk = 0; kk < 16; ++kk) {
    short8 afrag[4];
#pragma unroll
    for (int mi = 0; mi < 4; ++mi) {
      const float* ap = x + (size_t)(rowbase + mi * 16 + lo) * DIM + kk * 32 + hi * 8;
      float4 f0 = *(const float4*)ap;
      float4 f1 = *(const float4*)(ap + 4);
      Frag a;
      a.u[0] = f2bf(f0.x); a.u[1] = f2bf(f0.y); a.u[2] = f2bf(f0.z); a.u[3] = f2bf(f0.w);
      a.u[4] = f2bf(f1.x); a.u[5] = f2bf(f1.y); a.u[6] = f2bf(f1.z); a.u[7] = f2bf(f1.w);
      afrag[mi] = a.s;
    }
#pragma unroll
    for (int ni = 0; ni < 8; ++ni) {
      int cc = wave * 8 + ni;
      Frag b;
      b.v = wxb[(kk * 32 + cc) * 64 + lane];
#pragma unroll
      for (int mi = 0; mi < 4; ++mi)
        acc[mi][ni] = __builtin_amdgcn_mfma_f32_16x16x32_bf16(afrag[mi], b.s, acc[mi][ni], 0, 0, 0);
    }
  }
#pragma unroll
  for (int ni = 0; ni < 8; ++ni) {
    int col = wave * 128 + ni * 16 + lo;
    float bv = bias[col];
#pragma unroll
    for (int mi = 0; mi < 4; ++mi)
#pragma unroll
      for (int r = 0; r < 4; ++r) {
        int row = rowbase + mi * 16 + hi * 4 + r;
        out[(size_t)row * DIM + col] = acc[mi][ni][r] + bv;
      }
  }
}

// ---------------------------------------------------------------------------
// Recurrent scan (v7/v13 verbatim). grid = 4 blocks x 512 thr (8 waves, 2/SIMD).
// ---------------------------------------------------------------------------
__shared__ uint4 wlds[4][32][64];             // 128 KB: Wh kk=12..15
__shared__ unsigned short hbuf2[2][16 * 512]; // 32 KB ping/pong

template <int BUF>
static __device__ __forceinline__ void step_body(
    int t, int w, int lane, const uint4 (&bw)[12][4],
    const uint4* const (&rdp)[8], uint2* const (&wrp)[4],
    float (&xwv)[16], float*& gp) {
  // acc starts at xw (lane: n=lo, cols 64w + 16i + 4hi + r)
  f32x4 acc[4];
#pragma unroll
  for (int i = 0; i < 4; ++i)
    acc[i] = (f32x4){xwv[i * 4 + 0], xwv[i * 4 + 1], xwv[i * 4 + 2], xwv[i * 4 + 3]};

  // prefetch xw(t+1): 4x dwordx4, issued before MFMA phase
  const float* lp = gp + ((t < T_S - 1) ? DIM : 0);
#pragma unroll
  for (int i = 0; i < 4; ++i) {
    float4 f = *(const float4*)(lp + i * 16);
    xwv[i * 4 + 0] = f.x; xwv[i * 4 + 1] = f.y;
    xwv[i * 4 + 2] = f.z; xwv[i * 4 + 3] = f.w;
  }

  // kk 0..11: AGPR-resident weights as A; h frag as B (imm-offset reads)
#pragma unroll
  for (int kk = 0; kk < 12; ++kk) {
    Frag hf; hf.v = rdp[kk & 7][((kk & 8) ? 32 : 0) + BUF * 1024];
#pragma unroll
    for (int i = 0; i < 4; ++i) {
      Frag a; a.v = bw[kk][i];
      acc[i] = __builtin_amdgcn_mfma_f32_16x16x32_bf16(a.s, hf.s, acc[i], 0, 0, 0);
    }
  }
  // kk 12..15: LDS-resident weights (lane-contiguous uint4, conflict-free)
#pragma unroll
  for (int kk = 12; kk < 16; ++kk) {
    Frag hf; hf.v = rdp[kk & 7][32 + BUF * 1024];
#pragma unroll
    for (int i = 0; i < 4; ++i) {
      Frag a; a.v = wlds[kk - 12][w * 4 + i][lane];
      acc[i] = __builtin_amdgcn_mfma_f32_16x16x32_bf16(a.s, hf.s, acc[i], 0, 0, 0);
    }
  }

  // epilogue: lane owns n=lo, 4 consecutive cols per acc group
#pragma unroll
  for (int i = 0; i < 4; ++i) {
    float h0 = fast_tanh(acc[i][0]);
    float h1 = fast_tanh(acc[i][1]);
    float h2 = fast_tanh(acc[i][2]);
    float h3 = fast_tanh(acc[i][3]);
    *(float4*)(gp + i * 16) = (float4){h0, h1, h2, h3};   // out row n, 16B
    uint2 u;
    u.x = cvt_pk_bf16(h0, h1);
    u.y = cvt_pk_bf16(h2, h3);
    wrp[i][(BUF ^ 1) * 2048] = u;                          // ds_write_b64
  }
  gp += DIM;

  // one barrier per step: LDS h-writes visible; no vmem drain
  asm volatile("s_waitcnt lgkmcnt(0)" ::: "memory");
  __builtin_amdgcn_sched_barrier(0);
  __builtin_amdgcn_s_barrier();
  __builtin_amdgcn_sched_barrier(0);
}

__global__ __launch_bounds__(512, 2) void rnn_scan(const float* __restrict__ h0,
                                                   const uint4* __restrict__ whb,
                                                   float* __restrict__ out) {
  int g = blockIdx.x;
  int w = threadIdx.x >> 6, lane = threadIdx.x & 63;
  int lo = lane & 15, hi = lane >> 4;
  int msk = (lo & 7) << 4;

  // AGPR-resident Wh: kk 0..11 x this wave's 4 col-tiles = 192 regs
  uint4 bw[12][4];
#pragma unroll
  for (int kk = 0; kk < 12; ++kk)
#pragma unroll
    for (int i = 0; i < 4; ++i)
      bw[kk][i] = whb[(kk * 32 + (w * 4 + i)) * 64 + lane];

  // LDS-resident Wh: kk 12..15, all 32 cc (coalesced cooperative stage)
#pragma unroll
  for (int e = 0; e < 16; ++e) {
    int idx = e * 512 + threadIdx.x;
    int s = idx >> 11, rem = idx & 2047;
    wlds[s][rem >> 6][rem & 63] = whb[((12 + s) * 32 + (rem >> 6)) * 64 + (rem & 63)];
  }

  // loop-invariant LDS addresses (buffer 0 bases; +16384B via imm for buffer 1)
  // read (B=h frag): byte = lo*1024 + ((kk*64 + hi*16) ^ msk), kk=0..7
  const uint4* rdp[8];
#pragma unroll
  for (int kk = 0; kk < 8; ++kk)
    rdp[kk] = (const uint4*)((const char*)hbuf2 + lo * 1024 + ((kk * 64 + hi * 16) ^ msk));
  // write: byte = lo*1024 + (((64w + 16i + 4hi)*2) ^ msk), i=0..3 bases
  uint2* wrp[4];
#pragma unroll
  for (int i = 0; i < 4; ++i)
    wrp[i] = (uint2*)((char*)hbuf2 + lo * 1024 + ((128 * w + 32 * i + 8 * hi) ^ msk));

  // h_0 into buffer 0: lane loads h0[n=lo][c..c+3], packs, b64-writes
#pragma unroll
  for (int i = 0; i < 4; ++i) {
    const float* hp = h0 + (size_t)(g * 16 + lo) * DIM + w * 64 + i * 16 + hi * 4;
    float4 f = *(const float4*)hp;
    uint2 u;
    u.x = (unsigned)f2bf(f.x) | ((unsigned)f2bf(f.y) << 16);
    u.y = (unsigned)f2bf(f.z) | ((unsigned)f2bf(f.w) << 16);
    wrp[i][0] = u;
  }

  // running global pointer: lane -> out[n=16g+lo][t=0][64w + 4hi]
  float* gp = out + ((size_t)(g * 16 + lo) * T_S) * DIM + w * 64 + hi * 4;

  // prime xw for t=0
  float xwv[16];
#pragma unroll
  for (int i = 0; i < 4; ++i) {
    float4 f = *(const float4*)(gp + i * 16);
    xwv[i * 4 + 0] = f.x; xwv[i * 4 + 1] = f.y;
    xwv[i * 4 + 2] = f.z; xwv[i * 4 + 3] = f.w;
  }

  __syncthreads();  // heavy barrier once before the loop

#pragma unroll 1
  for (int t = 0; t < T_S; t += 2) {
    step_body<0>(t,     w, lane, bw, rdp, wrp, xwv, gp);
    step_body<1>(t + 1, w, lane, bw, rdp, wrp, xwv, gp);
  }
}

// ---------------------------------------------------------------------------
extern "C" void kernel_launch(void* const* d_in, const int* in_sizes, int n_in,
                              void* d_out, int out_size, void* d_ws, size_t ws_size,
                              hipStream_t stream) {
  const float* x  = (const float*)d_in[0];
  const float* h0 = (const float*)d_in[1];
  const float* Wx = (const float*)d_in[2];
  const float* Wh = (const float*)d_in[3];
  const float* b  = (const float*)d_in[4];
  float* out = (float*)d_out;

  char* ws = (char*)d_ws;
  uint4* whb = (uint4*)ws;                  // 512 KB
  uint4* wxb = (uint4*)(ws + 524288);       // 512 KB

  prepack<<<1024, 64, 0, stream>>>(Wx, Wh, wxb, whb);
  gemm_xw<<<512, 256, 0, stream>>>(x, wxb, b, out);
  rnn_scan<<<4, 512, 0, stream>>>(h0, whb, out);
}